// Round 1
// baseline (51.120 us; speedup 1.0000x reference)
//
#include <hip/hip_runtime.h>
#include <hip/hip_fp16.h>

// MultiScaleRoIAlign (round 5): vectorized repack.
// Pass 1 (rewritten): transpose pyramid [B,C,H,W] fp32 -> ws [B, hw, C] fp16.
//   - float4 global loads (16B/lane), ds_write_b128 into XOR-swizzled LDS tile,
//     column reads at <=2-way bank conflict, half8 (16B) global stores.
//   - old version was issue-bound: 4B/lane everywhere, 14.6% HBM, 7% VALU.
// Pass 2: unchanged verified per-roi gather (block = roi, lane owns 4 channels).

#define ROI_OUT 7
#define NSAMP   14
#define C_TOT   256
#define N_PER_B 256
#define BINS    49
#define TOT_HW  53125          // 40000 + 10000 + 2500 + 625 per image

// hw-tile counts per level (ceil(HW/64)): 625, 157, 40, 10 -> prefix 625,782,822,832
#define NTILE_X 832

// ---------------- pass 1: transpose to channels-last fp16 ----------------
// LDS float tile, logical [c][hw] (64x64), word index = c*64 + (hw4 ^ 4*swz(c)) + (hw&3)
// swz(c) = (c ^ (c>>3)) & 7  -> write side sweeps banks uniformly; read side
// (column of 8 consecutive c per lane) pairs lanes (laneC,hw) <-> (laneC^1,hw^4)
// on the same bank: exactly 2-way, which is free on CDNA4.
__device__ __forceinline__ int swz4(int c) { return ((c ^ (c >> 3)) & 7) << 2; }

__global__ __launch_bounds__(256)
void repack_kernel(const float* __restrict__ f0, const float* __restrict__ f1,
                   const float* __restrict__ f2, const float* __restrict__ f3,
                   __half* __restrict__ ws)
{
    __shared__ float tile[64 * 64];

    const int tx = blockIdx.x;
    const float* feat; int HW, base, hw0;
    if (tx < 625)      { feat = f0; HW = 40000; base = 0;     hw0 = tx * 64; }
    else if (tx < 782) { feat = f1; HW = 10000; base = 40000; hw0 = (tx - 625) * 64; }
    else if (tx < 822) { feat = f2; HW = 2500;  base = 50000; hw0 = (tx - 782) * 64; }
    else               { feat = f3; HW = 625;   base = 52500; hw0 = (tx - 822) * 64; }

    const int c0 = blockIdx.y * 64;
    const int b  = blockIdx.z;
    const float* src = feat + ((size_t)(b * C_TOT + c0)) * (size_t)HW + hw0;

    const int t    = threadIdx.x;
    const int hwq  = (t & 15) * 4;     // hw quad within tile
    const int crow = t >> 4;           // c row 0..15

    const bool fast = (hw0 + 64 <= HW) && ((HW & 3) == 0);  // full tile, float4-alignable

    if (fast) {
        #pragma unroll
        for (int i = 0; i < 4; ++i) {
            int c = crow + 16 * i;
            float4 v = *(const float4*)(src + (size_t)c * HW + hwq);
            *(float4*)&tile[c * 64 + (hwq ^ swz4(c))] = v;
        }
    } else {
        // partial tiles (tail of each level) + level 3 (HW=625, odd stride)
        #pragma unroll
        for (int i = 0; i < 4; ++i) {
            int c = crow + 16 * i;
            float* drow = &tile[c * 64 + (hwq ^ swz4(c))];
            #pragma unroll
            for (int k = 0; k < 4; ++k) {
                int hw = hw0 + hwq + k;
                drow[k] = (hw < HW) ? src[(size_t)c * HW + hwq + k] : 0.0f;
            }
        }
    }
    __syncthreads();

    // write out: lane owns 8 consecutive channels (16B) for one hw row;
    // 8 lanes cover 64 c = 128B contiguous per row, 8 rows per wave.
    const int cc0 = (t & 7) * 8;
    __half* dst = ws + ((size_t)b * TOT_HW + base) * C_TOT + c0 + cc0;
    #pragma unroll
    for (int it = 0; it < 2; ++it) {
        int hwr = (t >> 3) + 32 * it;          // 0..63
        int hw  = hw0 + hwr;
        if (hw < HW) {
            int hb = hwr & ~3, ho = hwr & 3;
            __half2 h[4];
            #pragma unroll
            for (int j = 0; j < 8; j += 2) {
                int ca = cc0 + j, cb = cc0 + j + 1;
                float fa = tile[ca * 64 + ((hb ^ swz4(ca)) + ho)];
                float fb = tile[cb * 64 + ((hb ^ swz4(cb)) + ho)];
                h[j >> 1] = __floats2half2_rn(fa, fb);
            }
            *(float4*)(dst + (size_t)hw * C_TOT) = *(const float4*)h;
        }
    }
}

// ---------------- pass 2: per-roi pooled gather (unchanged) ----------------
__global__ __launch_bounds__(256)
void msroi_main(const __half* __restrict__ ws, const float* __restrict__ boxes,
                float* __restrict__ out)
{
    __shared__ float oacc[C_TOT * BINS];   // [c][bin], 50176 B
    __shared__ int4  pY[NSAMP], pX[NSAMP];

    const int tid = threadIdx.x;
    const int roi = blockIdx.x;
    const int b   = roi >> 8;

    // box + level (block-uniform)
    const float* bxp = boxes + (size_t)roi * 4;
    float bx1 = bxp[0], by1 = bxp[1], bx2 = bxp[2], by2 = bxp[3];
    float area = (bx2 - bx1) * (by2 - by1);
    float s    = sqrtf(area);
    float lvlf = floorf(4.0f + log2f(s * (1.0f / 224.0f)) + 1e-6f);
    lvlf = fminf(fmaxf(lvlf, 2.0f), 5.0f);
    int level = (int)lvlf - 2;

    int H, W, lvbase; float scale;
    switch (level) {
        case 0:  H = 200; W = 200; lvbase = 0;     scale = 0.25f;    break;
        case 1:  H = 100; W = 100; lvbase = 40000; scale = 0.125f;   break;
        case 2:  H = 50;  W = 50;  lvbase = 50000; scale = 0.0625f;  break;
        default: H = 25;  W = 25;  lvbase = 52500; scale = 0.03125f; break;
    }

    float x1 = bx1 * scale, y1 = by1 * scale;
    float roi_w = fmaxf(bx2 * scale - x1, 1.0f);
    float roi_h = fmaxf(by2 * scale - y1, 1.0f);
    float bin_w = roi_w * (1.0f / ROI_OUT);
    float bin_h = roi_h * (1.0f / ROI_OUT);

    if (tid < 2 * NSAMP) {
        bool isy = tid >= NSAMP;
        int  j   = isy ? tid - NSAMP : tid;
        int  pb  = j >> 1, sub = j & 1;
        float start = isy ? y1 : x1;
        float bsz   = isy ? bin_h : bin_w;
        int   lim   = isy ? H : W;
        float ss = start + (float)pb * bsz + ((float)sub + 0.5f) * bsz * 0.5f;
        float v  = (ss >= -1.0f && ss <= (float)lim) ? 1.0f : 0.0f;
        float cc = fminf(fmaxf(ss, 0.0f), (float)lim - 1.0f);
        int   i0 = (int)floorf(cc);
        int   i1 = min(i0 + 1, lim - 1);
        float l  = cc - (float)i0;
        int4 pk; pk.x = i0; pk.y = i1;
        pk.z = __float_as_int(l); pk.w = __float_as_int(v);
        if (isy) pY[j] = pk; else pX[j] = pk;
    }
    __syncthreads();

    const int wave = tid >> 6;
    const int lane = tid & 63;
    const int c    = lane * 4;
    const __half* base = ws + ((size_t)b * TOT_HW + lvbase) * C_TOT + c;

    for (int bin = wave; bin < BINS; bin += 4) {
        int ph = bin / ROI_OUT;
        int pw = bin - ph * ROI_OUT;
        float a0 = 0.f, a1 = 0.f, a2 = 0.f, a3 = 0.f;

        #pragma unroll
        for (int sy = 0; sy < 2; ++sy) {
            int4 py  = pY[2 * ph + sy];
            float ly = __int_as_float(py.z);
            float vy = __int_as_float(py.w);
            float hy = 1.0f - ly;
            #pragma unroll
            for (int sx = 0; sx < 2; ++sx) {
                int4 px  = pX[2 * pw + sx];
                float lx = __int_as_float(px.z);
                float vv = vy * __int_as_float(px.w);
                float hx = 1.0f - lx;
                float w00 = vv * hy * hx, w01 = vv * hy * lx;
                float w10 = vv * ly * hx, w11 = vv * ly * lx;

                const __half2* p00 = (const __half2*)(base + (size_t)(py.x * W + px.x) * C_TOT);
                const __half2* p01 = (const __half2*)(base + (size_t)(py.x * W + px.y) * C_TOT);
                const __half2* p10 = (const __half2*)(base + (size_t)(py.y * W + px.x) * C_TOT);
                const __half2* p11 = (const __half2*)(base + (size_t)(py.y * W + px.y) * C_TOT);

                float2 g0, g1;
                g0 = __half22float2(p00[0]); g1 = __half22float2(p00[1]);
                a0 += w00 * g0.x; a1 += w00 * g0.y; a2 += w00 * g1.x; a3 += w00 * g1.y;
                g0 = __half22float2(p01[0]); g1 = __half22float2(p01[1]);
                a0 += w01 * g0.x; a1 += w01 * g0.y; a2 += w01 * g1.x; a3 += w01 * g1.y;
                g0 = __half22float2(p10[0]); g1 = __half22float2(p10[1]);
                a0 += w10 * g0.x; a1 += w10 * g0.y; a2 += w10 * g1.x; a3 += w10 * g1.y;
                g0 = __half22float2(p11[0]); g1 = __half22float2(p11[1]);
                a0 += w11 * g0.x; a1 += w11 * g0.y; a2 += w11 * g1.x; a3 += w11 * g1.y;
            }
        }
        oacc[(c + 0) * BINS + bin] = a0 * 0.25f;
        oacc[(c + 1) * BINS + bin] = a1 * 0.25f;
        oacc[(c + 2) * BINS + bin] = a2 * 0.25f;
        oacc[(c + 3) * BINS + bin] = a3 * 0.25f;
    }
    __syncthreads();

    // coalesced writeout: [c][bin] tile -> out[roi][c][7][7]
    float4*       o4 = (float4*)(out + (size_t)roi * (C_TOT * BINS));
    const float4* s4 = (const float4*)oacc;
    for (int j = tid; j < (C_TOT * BINS) / 4; j += 256) o4[j] = s4[j];
}

// ---------------- fallback: round-1 direct gather ----------------
__global__ __launch_bounds__(256)
void msroi_direct(const float* __restrict__ f0, const float* __restrict__ f1,
                  const float* __restrict__ f2, const float* __restrict__ f3,
                  const float* __restrict__ boxes, float* __restrict__ out, int total)
{
    int e = blockIdx.x * 256 + threadIdx.x;
    if (e >= total) return;
    int bin = e % BINS;
    int c   = (e / BINS) % C_TOT;
    int roi = e / (BINS * C_TOT);
    int b   = roi / N_PER_B;

    const float* bx = boxes + (size_t)roi * 4;
    float bx1 = bx[0], by1 = bx[1], bx2 = bx[2], by2 = bx[3];
    float area = (bx2 - bx1) * (by2 - by1);
    float s    = sqrtf(area);
    float lvlf = floorf(4.0f + log2f(s * (1.0f / 224.0f)) + 1e-6f);
    lvlf = fminf(fmaxf(lvlf, 2.0f), 5.0f);
    int level = (int)lvlf - 2;

    const float* feat; int H, W; float scale;
    switch (level) {
        case 0:  feat = f0; H = 200; W = 200; scale = 0.25f;    break;
        case 1:  feat = f1; H = 100; W = 100; scale = 0.125f;   break;
        case 2:  feat = f2; H = 50;  W = 50;  scale = 0.0625f;  break;
        default: feat = f3; H = 25;  W = 25;  scale = 0.03125f; break;
    }
    float x1 = bx1 * scale, y1 = by1 * scale;
    float roi_w = fmaxf(bx2 * scale - x1, 1.0f);
    float roi_h = fmaxf(by2 * scale - y1, 1.0f);
    float bin_w = roi_w * (1.0f / ROI_OUT);
    float bin_h = roi_h * (1.0f / ROI_OUT);
    int ph = bin / ROI_OUT, pw = bin - ph * ROI_OUT;
    const float* plane = feat + ((size_t)(b * C_TOT + c)) * (size_t)(H * W);
    float Hf = (float)H, Wf = (float)W, acc = 0.0f;
    #pragma unroll
    for (int sy = 0; sy < 2; ++sy) {
        float ys = y1 + (float)ph * bin_h + ((float)sy + 0.5f) * bin_h * 0.5f;
        float vy = (ys >= -1.0f && ys <= Hf) ? 1.0f : 0.0f;
        float y  = fminf(fmaxf(ys, 0.0f), Hf - 1.0f);
        int   y0 = (int)floorf(y);
        int   y1i = min(y0 + 1, H - 1);
        float ly = y - (float)y0, hy = 1.0f - ly;
        int ro0 = y0 * W, ro1 = y1i * W;
        #pragma unroll
        for (int sx = 0; sx < 2; ++sx) {
            float xs = x1 + (float)pw * bin_w + ((float)sx + 0.5f) * bin_w * 0.5f;
            float vx = (xs >= -1.0f && xs <= Wf) ? 1.0f : 0.0f;
            float x  = fminf(fmaxf(xs, 0.0f), Wf - 1.0f);
            int   x0 = (int)floorf(x);
            int   x1i = min(x0 + 1, W - 1);
            float lx = x - (float)x0, hx = 1.0f - lx;
            float v00 = plane[ro0 + x0],  v01 = plane[ro0 + x1i];
            float v10 = plane[ro1 + x0],  v11 = plane[ro1 + x1i];
            acc += vy * vx * (hy * (hx * v00 + lx * v01) + ly * (hx * v10 + lx * v11));
        }
    }
    out[e] = acc * 0.25f;
}

extern "C" void kernel_launch(void* const* d_in, const int* in_sizes, int n_in,
                              void* d_out, int out_size, void* d_ws, size_t ws_size,
                              hipStream_t stream)
{
    const float* f0    = (const float*)d_in[0];
    const float* f1    = (const float*)d_in[1];
    const float* f2    = (const float*)d_in[2];
    const float* f3    = (const float*)d_in[3];
    const float* boxes = (const float*)d_in[4];
    float* out = (float*)d_out;

    const size_t ws_needed = (size_t)2 * TOT_HW * C_TOT * sizeof(__half); // 54.4 MB
    if (ws_size >= ws_needed) {
        __half* ws = (__half*)d_ws;
        hipLaunchKernelGGL(repack_kernel, dim3(NTILE_X, 4, 2), dim3(256), 0, stream,
                           f0, f1, f2, f3, ws);
        hipLaunchKernelGGL(msroi_main, dim3(2 * N_PER_B), dim3(256), 0, stream,
                           ws, boxes, out);
    } else {
        int total = out_size;
        hipLaunchKernelGGL(msroi_direct, dim3((total + 255) / 256), dim3(256), 0, stream,
                           f0, f1, f2, f3, boxes, out, total);
    }
}